// Round 14
// baseline (452.694 us; speedup 1.0000x reference)
//
#include <hip/hip_runtime.h>

typedef _Float16 f16;
typedef _Float16 f16x8 __attribute__((ext_vector_type(8)));
typedef _Float16 f16x4v __attribute__((ext_vector_type(4)));
typedef float f32x4 __attribute__((ext_vector_type(4)));

#define THREADS 256
#define BM 128
#define BN 128
#define BKK 64

// weights are scaled by WSCALE when converted to f16 (denormal guard), epilogues descale
#define WSCALE 256.0f
#define WDESCALE (1.0f/256.0f)

// ---------------- reductions ----------------
static __device__ __forceinline__ float wred_sum(float x){
#pragma unroll
  for (int o = 32; o; o >>= 1) x += __shfl_xor(x, o);
  return x;
}
static __device__ __forceinline__ int wred_sumi(int x){
#pragma unroll
  for (int o = 32; o; o >>= 1) x += __shfl_xor(x, o);
  return x;
}
static __device__ __forceinline__ float bred_sum(float x){
  __shared__ float r[4];
  x = wred_sum(x);
  if ((threadIdx.x & 63) == 0) r[threadIdx.x >> 6] = x;
  __syncthreads();
  float s = r[0] + r[1] + r[2] + r[3];
  __syncthreads();
  return s;
}

// ---------------- generic 128x128 f16 MFMA GEMM core ----------------
// global_load_lds width=16 staging with BOTH-SIDES XOR swizzle (rule #21):
// linear LDS dest; global SOURCE slot permuted (c&7)^((c>>3)&7); read applies
// the same XOR -> bank-conflict-free (verified: SQ_LDS_BANK_CONFLICT = 0).
template<class Epi>
static __device__ __forceinline__ void gemm_core(const f16* A, const f16* BT,
                                                 int m0, int K, int N, int n0, Epi epi)
{
  __shared__ __align__(16) f16 Al[BM][BKK];
  __shared__ __align__(16) f16 Bl[BN][BKK];
  const int t = threadIdx.x;
  const int lane = t & 63, wave = t >> 6;
  const int wr = wave >> 1, wc = wave & 1;

  // hoisted per-thread staging source pointers, slot XOR-swizzled by row&7
  const f16* gA[4];
  const f16* gB[4];
#pragma unroll
  for (int i = 0; i < 4; ++i) {
    int c = i * THREADS + t;
    int r = c >> 3;
    int kc = (((c & 7) ^ (r & 7)) << 3);
    gA[i] = A + (size_t)(m0 + r) * K + kc;
    gB[i] = BT + (size_t)(n0 + r) * K + kc;
  }

  f32x4 acc[4][4];
#pragma unroll
  for (int i = 0; i < 4; ++i)
#pragma unroll
    for (int j = 0; j < 4; ++j)
#pragma unroll
      for (int r = 0; r < 4; ++r) acc[i][j][r] = 0.0f;

  f16* Als = &Al[0][0];
  f16* Bls = &Bl[0][0];

  for (int k0 = 0; k0 < K; k0 += BKK) {
    __syncthreads();
#pragma unroll
    for (int i = 0; i < 4; ++i) {
      int c = i * THREADS + t;
      __builtin_amdgcn_global_load_lds(
          (const __attribute__((address_space(1))) void*)(gA[i] + k0),
          (__attribute__((address_space(3))) void*)(Als + (size_t)c * 8), 16, 0, 0);
      __builtin_amdgcn_global_load_lds(
          (const __attribute__((address_space(1))) void*)(gB[i] + k0),
          (__attribute__((address_space(3))) void*)(Bls + (size_t)c * 8), 16, 0, 0);
    }
    __syncthreads();
#pragma unroll
    for (int kk = 0; kk < BKK; kk += 32) {
      const int lrow = lane & 15, lk = (lane >> 4) * 8;
      const int sx = (lrow & 7) << 3;                 // read-side XOR (matches source)
      f16x8 af[4], bf[4];
#pragma unroll
      for (int mf = 0; mf < 4; ++mf)
        af[mf] = *(const f16x8*)&Als[(size_t)(wr * 64 + mf * 16 + lrow) * BKK + ((kk + lk) ^ sx)];
#pragma unroll
      for (int nf = 0; nf < 4; ++nf)
        bf[nf] = *(const f16x8*)&Bls[(size_t)(wc * 64 + nf * 16 + lrow) * BKK + ((kk + lk) ^ sx)];
#pragma unroll
      for (int mf = 0; mf < 4; ++mf)
#pragma unroll
        for (int nf = 0; nf < 4; ++nf)
          acc[mf][nf] = __builtin_amdgcn_mfma_f32_16x16x32_f16(af[mf], bf[nf], acc[mf][nf], 0, 0, 0);
    }
  }
  const int lr4 = (lane >> 4) * 4, lc = lane & 15;
#pragma unroll
  for (int mf = 0; mf < 4; ++mf)
#pragma unroll
    for (int nf = 0; nf < 4; ++nf)
#pragma unroll
      for (int r = 0; r < 4; ++r) {
        int row = wr * 64 + mf * 16 + lr4 + r;
        int col = n0 + wc * 64 + nf * 16 + lc;
        epi(row, col, acc[mf][nf][r]);
      }
}

// ---------------- kernels ----------------
__global__ __launch_bounds__(256) void k_cvt(const float* x, f16* o){
  size_t i = (size_t)blockIdx.x * 256 + threadIdx.x;
  float4 v = ((const float4*)x)[i];
  f16x4v h;
  h[0] = (f16)v.x; h[1] = (f16)v.y; h[2] = (f16)v.z; h[3] = (f16)v.w;
  *(f16x4v*)(o + i * 4) = h;
}

__global__ __launch_bounds__(256) void k_transpose(const float* in, f16* out, int Kd, int Nd){
  __shared__ float tl[32][33];
  const float* ip = in + (size_t)blockIdx.z * Kd * Nd;
  f16* op = out + (size_t)blockIdx.z * Kd * Nd;
  int n0 = blockIdx.x * 32, k0 = blockIdx.y * 32;
  int tx = threadIdx.x & 31, ty = threadIdx.x >> 5;
#pragma unroll
  for (int j = 0; j < 32; j += 8) tl[ty + j][tx] = ip[(size_t)(k0 + ty + j) * Nd + n0 + tx];
  __syncthreads();
#pragma unroll
  for (int j = 0; j < 32; j += 8) op[(size_t)(n0 + ty + j) * Kd + k0 + tx] = (f16)(tl[tx][ty + j] * WSCALE);
}

__global__ __launch_bounds__(256) void k_gemm_qkv(const f16* xb,
    const f16* wqT, const f16* wkT, const f16* wvT,
    const float* bq, const float* bk, const float* bv,
    f16* Q, f16* Ko, f16* V)
{
  int m0 = blockIdx.x * 128, n0 = blockIdx.y * 128, z = blockIdx.z;
  const f16* BT = (z == 0) ? wqT : ((z == 1) ? wkT : wvT);
  const float* bias = (z == 0) ? bq : ((z == 1) ? bk : bv);
  auto epi = [&](int row, int col, float vv) {
    int grow = m0 + row;
    int b = grow >> 11, s = grow & 2047;
    int h = col >> 6, dh = col & 63;
    float val = vv * WDESCALE + bias[col];
    if (z == 2) V[(((size_t)b * 12 + h) * 64 + dh) * 2048 + s] = (f16)val;
    else ((z == 0) ? Q : Ko)[(((size_t)b * 12 + h) * 2048 + s) * 64 + dh] = (f16)val;
  };
  gemm_core(xb, BT, m0, 768, 768, n0, epi);
}

// ---------------- fused flash attention (v3: split-KV, additive combine) ----
__global__ __launch_bounds__(256, 4) void k_fattn(const f16* Qf, const f16* Kf,
                                                  const f16* Vf, float* Opart, float* lpart)
{
  __shared__ __align__(16) f16 Kl[64][72];
  __shared__ __align__(16) f16 Vl[64][72];
  __shared__ __align__(16) f16 Pl[64][72];
  const int t = threadIdx.x, lane = t & 63, wid = t >> 6;
  const int lc = lane & 15, g = lane >> 4;
  const int q0 = blockIdx.x * 64, bh = blockIdx.y, sp = blockIdx.z;
  const f16* Qh = Qf + (size_t)bh * 2048 * 64;
  const f16* Kh = Kf + ((size_t)bh * 2048 + sp * 1024) * 64;
  const f16* Vh = Vf + (size_t)bh * 64 * 2048 + sp * 1024;

  const float C1 = 0.125f * 1.44269504f;
  const float C2 = 9.0f - 2.0f * 1.44269504f;

  f16x8 aq[2];
#pragma unroll
  for (int kk = 0; kk < 2; ++kk)
    aq[kk] = *(const f16x8*)(Qh + (size_t)(q0 + wid * 16 + lc) * 64 + kk * 32 + g * 8);

  f32x4 acco[4];
  float l_[4];
#pragma unroll
  for (int nf = 0; nf < 4; ++nf)
#pragma unroll
    for (int r = 0; r < 4; ++r) acco[nf][r] = 0.f;
#pragma unroll
  for (int r = 0; r < 4; ++r) l_[r] = 0.f;

  f16x8 sk[2], sv[2];
#pragma unroll
  for (int i = 0; i < 2; ++i) {
    int c = i * 256 + t;
    sk[i] = *(const f16x8*)(Kh + (size_t)(c >> 3) * 64 + (c & 7) * 8);
    sv[i] = *(const f16x8*)(Vh + (size_t)(c >> 3) * 2048 + (c & 7) * 8);
  }

  for (int j = 0; j < 16; ++j) {
    __syncthreads();
#pragma unroll
    for (int i = 0; i < 2; ++i) {
      int c = i * 256 + t;
      *(f16x8*)&Kl[c >> 3][(c & 7) * 8] = sk[i];
      *(f16x8*)&Vl[c >> 3][(c & 7) * 8] = sv[i];
    }
    __syncthreads();

    if (j < 15) {
      const int kv1 = (j + 1) * 64;
#pragma unroll
      for (int i = 0; i < 2; ++i) {
        int c = i * 256 + t;
        sk[i] = *(const f16x8*)(Kh + (size_t)(kv1 + (c >> 3)) * 64 + (c & 7) * 8);
        sv[i] = *(const f16x8*)(Vh + (size_t)(c >> 3) * 2048 + kv1 + (c & 7) * 8);
      }
    }

    f32x4 acc[4];
#pragma unroll
    for (int nf = 0; nf < 4; ++nf)
#pragma unroll
      for (int r = 0; r < 4; ++r) acc[nf][r] = 0.f;
#pragma unroll
    for (int kk = 0; kk < 2; ++kk) {
      f16x8 bk[4];
#pragma unroll
      for (int nf = 0; nf < 4; ++nf) bk[nf] = *(const f16x8*)&Kl[nf * 16 + lc][kk * 32 + g * 8];
#pragma unroll
      for (int nf = 0; nf < 4; ++nf)
        acc[nf] = __builtin_amdgcn_mfma_f32_16x16x32_f16(aq[kk], bk[nf], acc[nf], 0, 0, 0);
    }

    {
      const int prow = wid * 16 + g * 4;
#pragma unroll
      for (int r = 0; r < 4; ++r) {
        float ls = 0.f;
#pragma unroll
        for (int nf = 0; nf < 4; ++nf) {
          float p = exp2f(fmaf(acc[nf][r], C1, C2));   // = 512*exp(score-2)
          Pl[prow + r][nf * 16 + lc] = (f16)p;
          ls += p;
        }
        l_[r] += ls;
      }
    }

#pragma unroll
    for (int kk = 0; kk < 2; ++kk) {
      f16x8 ap, bv[4];
      ap = *(const f16x8*)&Pl[wid * 16 + lc][kk * 32 + g * 8];
#pragma unroll
      for (int nf = 0; nf < 4; ++nf) bv[nf] = *(const f16x8*)&Vl[nf * 16 + lc][kk * 32 + g * 8];
#pragma unroll
      for (int nf = 0; nf < 4; ++nf)
        acco[nf] = __builtin_amdgcn_mfma_f32_16x16x32_f16(ap, bv[nf], acco[nf], 0, 0, 0);
    }
  }

  float* Op = Opart + ((size_t)(sp * 24 + bh) * 2048 + q0) * 64;
  float* lp = lpart + (size_t)(sp * 24 + bh) * 2048 + q0;
#pragma unroll
  for (int r = 0; r < 4; ++r) {
    float lr = l_[r];
#pragma unroll
    for (int o = 1; o < 16; o <<= 1) lr += __shfl_xor(lr, o);
    if (lc == 0) lp[wid * 16 + g * 4 + r] = lr;
#pragma unroll
    for (int nf = 0; nf < 4; ++nf)
      Op[(size_t)(wid * 16 + g * 4 + r) * 64 + nf * 16 + lc] = acco[nf][r];
  }
}

// combine: ctx = (O0+O1)/(l0+l1); 4 elems/thread
__global__ __launch_bounds__(256) void k_attcomb(const float* Opart, const float* lpart, f16* ctx){
  size_t base = ((size_t)blockIdx.x * 256 + threadIdx.x) * 4;   // over 24*2048*64
  size_t row = base >> 6; int dh = base & 63;
  int bh = (int)(row >> 11), qr = (int)(row & 2047);
  int b = bh / 12, h = bh - b * 12;
  const float4 o0 = *(const float4*)(Opart + base);
  const float4 o1 = *(const float4*)(Opart + base + (size_t)24 * 2048 * 64);
  float inv = 1.f / (lpart[row] + lpart[row + 24 * 2048]);
  f16x4v hv;
  hv[0] = (f16)((o0.x + o1.x) * inv);
  hv[1] = (f16)((o0.y + o1.y) * inv);
  hv[2] = (f16)((o0.z + o1.z) * inv);
  hv[3] = (f16)((o0.w + o1.w) * inv);
  *(f16x4v*)(ctx + ((size_t)b * 2048 + qr) * 768 + h * 64 + dh) = hv;
}

__global__ __launch_bounds__(256) void k_gemm_oproj(const f16* ctx, const f16* woT,
    const float* bo, const float* x, float* x1pre)
{
  int m0 = blockIdx.x * 128, n0 = blockIdx.y * 128;
  auto epi = [&](int row, int col, float vv) {
    size_t i = (size_t)(m0 + row) * 768 + col;
    x1pre[i] = x[i] + vv * WDESCALE + bo[col];
  };
  gemm_core(ctx, woT, m0, 768, 768, n0, epi);
}

__global__ __launch_bounds__(256) void k_ln(const float* in, const float* add,
    const float* g, const float* b, float* outf, f16* outh)
{
  size_t row = blockIdx.x;
  int t = threadIdx.x;
  const float* p = in + row * 768;
  float v[3];
  float s = 0.f;
#pragma unroll
  for (int i = 0; i < 3; ++i) {
    float xv = p[t + i * 256];
    if (add) xv += add[row * 768 + t + i * 256];
    v[i] = xv; s += xv;
  }
  float mu = bred_sum(s) * (1.f / 768.f);
  float q = 0.f;
#pragma unroll
  for (int i = 0; i < 3; ++i) { float d = v[i] - mu; q += d * d; }
  float var = bred_sum(q) * (1.f / 768.f);
  float inv = rsqrtf(var + 1e-5f);
#pragma unroll
  for (int i = 0; i < 3; ++i) {
    int c = t + i * 256;
    float y = (v[i] - mu) * inv * g[c] + b[c];
    outf[row * 768 + c] = y;
    if (outh) outh[row * 768 + c] = (f16)y;
  }
}

// fused MoE-combine + LayerNorm: val = x1 + g0*y[slot0] + g1*y[slot1], then LN
__global__ __launch_bounds__(256) void k_ln_moe(const float* x1, const f16* ys,
    const int* inv_map, const float* gates, const float* g, const float* b, float* outf)
{
  size_t row = blockIdx.x;
  int t = threadIdx.x;
  int sl0 = inv_map[row * 2], sl1 = inv_map[row * 2 + 1];
  float g0 = gates[row * 2], g1 = gates[row * 2 + 1];
  const float* p = x1 + row * 768;
  const f16* y0 = ys + (size_t)sl0 * 768;
  const f16* y1 = ys + (size_t)sl1 * 768;
  float v[3];
  float s = 0.f;
#pragma unroll
  for (int i = 0; i < 3; ++i) {
    int c = t + i * 256;
    float xv = p[c] + g0 * (float)y0[c] + g1 * (float)y1[c];
    v[i] = xv; s += xv;
  }
  float mu = bred_sum(s) * (1.f / 768.f);
  float q = 0.f;
#pragma unroll
  for (int i = 0; i < 3; ++i) { float d = v[i] - mu; q += d * d; }
  float var = bred_sum(q) * (1.f / 768.f);
  float inv = rsqrtf(var + 1e-5f);
#pragma unroll
  for (int i = 0; i < 3; ++i) {
    int c = t + i * 256;
    outf[row * 768 + c] = (v[i] - mu) * inv * g[c] + b[c];
  }
}

// one wave per token. mode 1: write topi+gates (NO atomics).
// mode 2: per-block partial probsum/top2-count -> pprob_part/pcnt_part [block][8].
__global__ __launch_bounds__(256) void k_router(const float* X, const float* rw, const float* rb,
    int* topi, float* gates, float* pprob_part, int* pcnt_part, int mode)
{
  __shared__ float sp[4][8];
  __shared__ int   si[4][2];
  int wave = threadIdx.x >> 6;
  int tok = blockIdx.x * 4 + wave;
  int lane = threadIdx.x & 63;
  const float* xr = X + (size_t)tok * 768;
  float a0=0,a1=0,a2=0,a3=0,a4=0,a5=0,a6=0,a7=0;
#pragma unroll
  for (int i = 0; i < 12; ++i) {
    int d = lane + i * 64;
    float xv = xr[d];
    float4 w0 = *(const float4*)(rw + d * 8);
    float4 w1 = *(const float4*)(rw + d * 8 + 4);
    a0 += xv*w0.x; a1 += xv*w0.y; a2 += xv*w0.z; a3 += xv*w0.w;
    a4 += xv*w1.x; a5 += xv*w1.y; a6 += xv*w1.z; a7 += xv*w1.w;
  }
  a0=wred_sum(a0); a1=wred_sum(a1); a2=wred_sum(a2); a3=wred_sum(a3);
  a4=wred_sum(a4); a5=wred_sum(a5); a6=wred_sum(a6); a7=wred_sum(a7);
  if (lane == 0) {
    float lg[8] = {a0+rb[0],a1+rb[1],a2+rb[2],a3+rb[3],a4+rb[4],a5+rb[5],a6+rb[6],a7+rb[7]};
    float mx = lg[0];
    for (int e = 1; e < 8; ++e) mx = fmaxf(mx, lg[e]);
    float pp[8], ssum = 0.f;
    for (int e = 0; e < 8; ++e) { pp[e] = expf(lg[e] - mx); ssum += pp[e]; }
    float invs = 1.f / ssum;
    for (int e = 0; e < 8; ++e) pp[e] *= invs;
    int i1 = 0; float p1 = pp[0];
    for (int e = 1; e < 8; ++e) if (pp[e] > p1) { p1 = pp[e]; i1 = e; }
    int i2 = -1; float p2 = -1.f;
    for (int e = 0; e < 8; ++e) if (e != i1 && pp[e] > p2) { p2 = pp[e]; i2 = e; }
    if (mode == 1) {
      float gs = 1.f / (p1 + p2);
      topi[tok*2] = i1; topi[tok*2+1] = i2;
      gates[tok*2] = p1*gs; gates[tok*2+1] = p2*gs;
    } else {
      for (int e = 0; e < 8; ++e) sp[wave][e] = pp[e];
      si[wave][0] = i1; si[wave][1] = i2;
    }
  }
  if (mode == 2) {
    __syncthreads();
    int t = threadIdx.x;
    if (t < 8) {
      float s = sp[0][t] + sp[1][t] + sp[2][t] + sp[3][t];
      int c = 0;
#pragma unroll
      for (int w = 0; w < 4; ++w) c += (si[w][0] == t) + (si[w][1] == t);
      pprob_part[blockIdx.x * 8 + t] = s;
      pcnt_part[blockIdx.x * 8 + t] = c;
    }
  }
}

// single block: histogram of topi, then serial tile plans.
// Experts padded to 256 rows. tile_e/tile_r0: 256-row tiles (moe1, cap 40);
// tile_e2/tile_r02: 128-row tiles over the same ranges (moe2, cap 80).
__global__ __launch_bounds__(256) void k_plan(const int* topi, int* offal,
    int* tile_e, int* tile_r0, int* tile_e2, int* tile_r02)
{
  __shared__ int hist[8];
  int t = threadIdx.x, lane = t & 63;
  if (t < 8) hist[t] = 0;
  __syncthreads();
  int loc[8] = {0,0,0,0,0,0,0,0};
  for (int i = t; i < 8192; i += 256) ++loc[topi[i]];
#pragma unroll
  for (int e = 0; e < 8; ++e) {
    int s = wred_sumi(loc[e]);
    if (lane == 0) atomicAdd(&hist[e], s);
  }
  __syncthreads();
  if (t == 0) {
    int off = 0, t1 = 0, t2 = 0;
    for (int e = 0; e < 8; ++e) {
      offal[e] = off;
      int nt = (hist[e] + 255) >> 8;
      for (int i = 0; i < nt; ++i) {
        tile_e[t1] = e; tile_r0[t1] = off + i * 256; ++t1;
        tile_e2[t2] = e; tile_r02[t2] = off + i * 256; ++t2;
        tile_e2[t2] = e; tile_r02[t2] = off + i * 256 + 128; ++t2;
      }
      off += nt << 8;
    }
    for (; t1 < 40; ++t1) { tile_e[t1] = -1; tile_r0[t1] = 0; }
    for (; t2 < 80; ++t2) { tile_e2[t2] = -1; tile_r02[t2] = 0; }
  }
}

// one block, 8 waves; wave w compacts expert w's slots via ballot prefix (no atomics)
// also records inverse map: inv[tok*2+k] = slot
__global__ __launch_bounds__(512) void k_scatter(const int* topi, const float* gates,
    const int* offal, int* perm, float* gate_s, int* inv_map)
{
  int w = threadIdx.x >> 6, lane = threadIdx.x & 63;
  int base = offal[w];
  for (int it = 0; it < 128; ++it) {
    int i = it * 64 + lane;
    int e = topi[i];
    bool act = (e == w);
    unsigned long long mask = __ballot(act);
    if (act) {
      int pos = base + __popcll(mask & ((1ull << lane) - 1ull));
      perm[pos] = i >> 1;
      gate_s[pos] = gates[i];
      inv_map[i] = pos;
    }
    base += __popcll(mask);
  }
}

// ---------------- moe1: 256x256 tile, 512 thr, dbuf, COUNTED-vmcnt pipeline --
__global__ __launch_bounds__(512, 1) void k_gemm_moe1(const f16* x1b, const f16* ew1T,
    const float* eb1, const int* tile_e, const int* tile_r0, const int* perm, f16* hbuf)
{
  __shared__ __align__(16) f16 Al[2][256][64];
  __shared__ __align__(16) f16 Bl[2][256][64];
  int e = tile_e[blockIdx.x];
  if (e < 0) return;
  int s0 = tile_r0[blockIdx.x];
  int n0 = blockIdx.y * 256;
  const f16* BT = ew1T + (size_t)e * 3072 * 768 + (size_t)n0 * 768;
  const float* be = eb1 + e * 3072;

  const int t = threadIdx.x;               // 0..511
  const int lane = t & 63, wave = t >> 6;  // 8 waves
  const int wr = wave >> 2, wc = wave & 3; // 2 x 4

  const f16* gA[4];
  const f16* gB[4];
#pragma unroll
  for (int i = 0; i < 4; ++i) {
    int c = i * 512 + t;                   // 0..2047
    int r = c >> 3;                        // 0..255
    int kc = (((c & 7) ^ (r & 7)) << 3);
    gA[i] = x1b + (size_t)perm[s0 + r] * 768 + kc;
    gB[i] = BT + (size_t)r * 768 + kc;
  }

  f32x4 acc[8][4];
#pragma unroll
  for (int i = 0; i < 8; ++i)
#pragma unroll
    for (int j = 0; j < 4; ++j)
#pragma unroll
      for (int r = 0; r < 4; ++r) acc[i][j][r] = 0.0f;

  auto stage = [&](int buf, int k0) {
    f16* Ad = &Al[buf][0][0];
    f16* Bd = &Bl[buf][0][0];
#pragma unroll
    for (int i = 0; i < 4; ++i) {
      int c = i * 512 + t;
      __builtin_amdgcn_global_load_lds(
          (const __attribute__((address_space(1))) void*)(gA[i] + k0),
          (__attribute__((address_space(3))) void*)(Ad + (size_t)c * 8), 16, 0, 0);
      __builtin_amdgcn_global_load_lds(
          (const __attribute__((address_space(1))) void*)(gB[i] + k0),
          (__attribute__((address_space(3))) void*)(Bd + (size_t)c * 8), 16, 0, 0);
    }
  };

  // prologue: two K-tiles in flight
  stage(0, 0);
  stage(1, 64);

  for (int ks = 0; ks < 12; ++ks) {
    const int cur = ks & 1;
    if (ks < 11) asm volatile("s_waitcnt vmcnt(8)" ::: "memory");
    else         asm volatile("s_waitcnt vmcnt(0)" ::: "memory");
    __builtin_amdgcn_s_barrier();
    asm volatile("" ::: "memory");

    const f16* Ab = &Al[cur][0][0];
    const f16* Bb = &Bl[cur][0][0];
#pragma unroll
    for (int kk = 0; kk < 64; kk += 32) {
      const int lrow = lane & 15, lk = (lane >> 4) * 8;
      const int sx = (lrow & 7) << 3;
      f16x8 af[8], bf[4];
#pragma unroll
      for (int mf = 0; mf < 8; ++mf)
        af[mf] = *(const f16x8*)&Ab[(size_t)(wr * 128 + mf * 16 + lrow) * 64 + ((kk + lk) ^ sx)];
#pragma unroll
      for (int nf = 0; nf < 4; ++nf)
        bf[nf] = *(const f16x8*)&Bb[(size_t)(wc * 64 + nf * 16 + lrow) * 64 + ((kk + lk) ^ sx)];
#pragma unroll
      for (int mf = 0; mf < 8; ++mf)
#pragma unroll
        for (int nf = 0; nf < 4; ++nf)
          acc[mf][nf] = __builtin_amdgcn_mfma_f32_16x16x32_f16(af[mf], bf[nf], acc[mf][nf], 0, 0, 0);
    }

    asm volatile("" ::: "memory");
    __builtin_amdgcn_s_barrier();
    asm volatile("" ::: "memory");
    if (ks < 10) stage(cur, (ks + 2) * 64);
  }

  const int lr4 = (lane >> 4) * 4, lc = lane & 15;
#pragma unroll
  for (int mf = 0; mf < 8; ++mf)
#pragma unroll
    for (int nf = 0; nf < 4; ++nf)
#pragma unroll
      for (int r = 0; r < 4; ++r) {
        int row = wr * 128 + mf * 16 + lr4 + r;
        int col = n0 + wc * 64 + nf * 16 + lc;
        hbuf[(size_t)(s0 + row) * 3072 + col] = (f16)fmaxf(acc[mf][nf][r] * WDESCALE + be[col], 0.f);
      }
}

// moe2: 128x128 2-phase core; grid (6,80) with n0 FASTEST so the 6 blocks
// sharing one 768KB A-panel (hbuf tile) dispatch adjacently -> A re-reads
// hit L2/L3 instead of HBM.
__global__ __launch_bounds__(256) void k_gemm_moe2(const f16* hbuf, const f16* ew2T,
    const float* eb2, const int* tile_e2, const int* tile_r02, f16* yslots)
{
  int tile = blockIdx.y;
  int e = tile_e2[tile];
  if (e < 0) return;
  int s0 = tile_r02[tile];
  int n0 = blockIdx.x * 128;
  const f16* A = hbuf + (size_t)s0 * 3072;
  const f16* BT = ew2T + (size_t)e * 768 * 3072;
  const float* be = eb2 + e * 768;
  auto epi = [&](int row, int col, float vv) {
    yslots[(size_t)(s0 + row) * 768 + col] = (f16)(vv * WDESCALE + be[col]);
  };
  gemm_core(A, BT, 0, 3072, 768, n0, epi);
}

// reduce [1024][8] partials -> aux loss (MUST be launched with 256 threads)
__global__ __launch_bounds__(256) void k_final(const float* pprob, const int* pcnt, float* out){
  __shared__ float sp[256];
  __shared__ int sc[256];
  int t = threadIdx.x, e = t & 7, g = t >> 3;
  float s = 0.f; int c = 0;
  for (int b = g; b < 1024; b += 32) { s += pprob[b * 8 + e]; c += pcnt[b * 8 + e]; }
  sp[t] = s; sc[t] = c;
  __syncthreads();
  if (t < 8) {
    float ss = 0.f; int cc = 0;
    for (int g2 = 0; g2 < 32; ++g2) { ss += sp[t + g2 * 8]; cc += sc[t + g2 * 8]; }
    sp[t] = ss; sc[t] = cc;
  }
  __syncthreads();
  if (t == 0) {
    float a = 0.f;
    for (int e2 = 0; e2 < 8; ++e2)
      a += ((float)sc[e2] * (1.f / 8192.f)) * (sp[e2] * (1.f / 4096.f));
    out[(size_t)4096 * 768] = 8.f * a;
  }
}

// ---------------- host ----------------
extern "C" void kernel_launch(void* const* d_in, const int* in_sizes, int n_in,
                              void* d_out, int out_size, void* d_ws, size_t ws_size,
                              hipStream_t stream)
{
  const float* x   = (const float*)d_in[0];
  const float* wq  = (const float*)d_in[1];
  const float* bq  = (const float*)d_in[2];
  const float* wk  = (const float*)d_in[3];
  const float* bk  = (const float*)d_in[4];
  const float* wv  = (const float*)d_in[5];
  const float* bv  = (const float*)d_in[6];
  const float* wo  = (const float*)d_in[7];
  const float* bo  = (const float*)d_in[8];
  const float* n1g = (const float*)d_in[9];
  const float* n1b = (const float*)d_in[10];
  const float* rw  = (const float*)d_in[11];
  const float* rb  = (const float*)d_in[12];
  const float* ew1 = (const float*)d_in[13];
  const float* eb1 = (const float*)d_in[14];
  const float* ew2 = (const float*)d_in[15];
  const float* eb2 = (const float*)d_in[16];
  const float* n2g = (const float*)d_in[17];
  const float* n2b = (const float*)d_in[18];
  float* out = (float*)d_out;
  char* ws = (char*)d_ws;

  size_t oWQT,oWKT,oWVT,oWOT,oEW1T,oEW2T,oXB,oQ,oK,oV,oCTX,oX1,oX1B,oYS;
  size_t oTOPI,oGATES,oOFF,oTE,oTR,oTE2,oTR2,oPERM,oGS,oINV,oH,oPP,oPC,oOP,oLP;

  {
    size_t off = 0;
    auto al = [&](size_t bytes) { size_t o = off; off += (bytes + 255) & ~(size_t)255; return o; };
    oWQT = al((size_t)768*768*2); oWKT = al((size_t)768*768*2);
    oWVT = al((size_t)768*768*2); oWOT = al((size_t)768*768*2);
    oEW1T = al((size_t)8*768*3072*2); oEW2T = al((size_t)8*768*3072*2);
    oXB  = al((size_t)4096*768*2);
    oQ   = al((size_t)24*2048*64*2); oK = al((size_t)24*2048*64*2); oV = al((size_t)24*2048*64*2);
    oCTX = al((size_t)4096*768*2);
    oX1  = al((size_t)4096*768*4);
    oX1B = al((size_t)4096*768*2);
    oYS  = al((size_t)10240*768*2);
    oTOPI = al(4096*2*4); oGATES = al(4096*2*4);
    oOFF = al(256);
    oTE = al(256); oTR = al(256); oTE2 = al(512); oTR2 = al(512);
    oPERM = al(10240*4); oGS = al(10240*4); oINV = al(8192*4);
    oH = al((size_t)10240*3072*2);
    oPP = al(1024*8*4); oPC = al(1024*8*4);
    oOP = al((size_t)2*24*2048*64*4);
    oLP = al((size_t)2*24*2048*4);
    (void)ws_size;
  }

  f16* wqT  = (f16*)(ws + oWQT);
  f16* wkT  = (f16*)(ws + oWKT);
  f16* wvT  = (f16*)(ws + oWVT);
  f16* woT  = (f16*)(ws + oWOT);
  f16* ew1T = (f16*)(ws + oEW1T);
  f16* ew2T = (f16*)(ws + oEW2T);
  f16* xb   = (f16*)(ws + oXB);
  f16* Qf   = (f16*)(ws + oQ);
  f16* Kf   = (f16*)(ws + oK);
  f16* Vf   = (f16*)(ws + oV);
  f16* ctxb = (f16*)(ws + oCTX);
  float* x1 = (float*)(ws + oX1);
  f16* x1bb = (f16*)(ws + oX1B);
  f16* yslots = (f16*)(ws + oYS);
  int* topi = (int*)(ws + oTOPI);
  float* gates = (float*)(ws + oGATES);
  int* offal  = (int*)(ws + oOFF);
  int* tile_e = (int*)(ws + oTE);
  int* tile_r0= (int*)(ws + oTR);
  int* tile_e2 = (int*)(ws + oTE2);
  int* tile_r02= (int*)(ws + oTR2);
  int* perm   = (int*)(ws + oPERM);
  float* gate_s = (float*)(ws + oGS);
  int* inv_map = (int*)(ws + oINV);
  f16* hbuf   = (f16*)(ws + oH);
  float* pprob = (float*)(ws + oPP);
  int* pcnt   = (int*)(ws + oPC);
  float* Opart = (float*)(ws + oOP);
  float* lpart = (float*)(ws + oLP);

  (void)in_sizes; (void)n_in; (void)out_size;

  // zero: perm/gate_s padding (contiguous, 10240 each)
  hipMemsetAsync(ws + oPERM, 0, 2 * 10240 * 4, stream);

  // convert inputs
  k_cvt<<<3072, 256, 0, stream>>>(x, xb);
  k_transpose<<<dim3(24,24,1), 256, 0, stream>>>(wq, wqT, 768, 768);
  k_transpose<<<dim3(24,24,1), 256, 0, stream>>>(wk, wkT, 768, 768);
  k_transpose<<<dim3(24,24,1), 256, 0, stream>>>(wv, wvT, 768, 768);
  k_transpose<<<dim3(24,24,1), 256, 0, stream>>>(wo, woT, 768, 768);
  k_transpose<<<dim3(96,24,8), 256, 0, stream>>>(ew1, ew1T, 768, 3072);
  k_transpose<<<dim3(24,96,8), 256, 0, stream>>>(ew2, ew2T, 3072, 768);

  // attention: QKV projection + fused flash attention (split-KV) + combine
  k_gemm_qkv<<<dim3(32,6,3), 256, 0, stream>>>(xb, wqT, wkT, wvT, bq, bk, bv, Qf, Kf, Vf);
  k_fattn<<<dim3(32,24,2), 256, 0, stream>>>(Qf, Kf, Vf, Opart, lpart);
  k_attcomb<<<3072, 256, 0, stream>>>(Opart, lpart, ctxb);
  k_gemm_oproj<<<dim3(32,6), 256, 0, stream>>>(ctxb, woT, bo, x, x1);
  k_ln<<<4096, 256, 0, stream>>>(x1, nullptr, n1g, n1b, x1, x1bb);

  // MoE routing + grouped experts (atomic-free end to end)
  k_router<<<1024, 256, 0, stream>>>(x1, rw, rb, topi, gates, pprob, pcnt, 1);
  k_plan<<<1, 256, 0, stream>>>(topi, offal, tile_e, tile_r0, tile_e2, tile_r02);
  k_scatter<<<1, 512, 0, stream>>>(topi, gates, offal, perm, gate_s, inv_map);
  k_gemm_moe1<<<dim3(40,12), 512, 0, stream>>>(x1bb, ew1T, eb1, tile_e, tile_r0, perm, hbuf);
  k_gemm_moe2<<<dim3(6,80), 256, 0, stream>>>(hbuf, ew2T, eb2, tile_e2, tile_r02, yslots);

  // fused combine + final LN -> output, then aux loss
  k_ln_moe<<<4096, 256, 0, stream>>>(x1, yslots, inv_map, gates, n2g, n2b, out);
  k_router<<<1024, 256, 0, stream>>>(out, rw, rb, topi, gates, pprob, pcnt, 2);
  k_final<<<1, 256, 0, stream>>>(pprob, pcnt, out);
}

// Round 15
// 432.006 us; speedup vs baseline: 1.0479x; 1.0479x over previous
//
#include <hip/hip_runtime.h>

typedef _Float16 f16;
typedef _Float16 f16x8 __attribute__((ext_vector_type(8)));
typedef _Float16 f16x4v __attribute__((ext_vector_type(4)));
typedef float f32x4 __attribute__((ext_vector_type(4)));

#define THREADS 256
#define BM 128
#define BN 128
#define BKK 64

// weights are scaled by WSCALE when converted to f16 (denormal guard), epilogues descale
#define WSCALE 256.0f
#define WDESCALE (1.0f/256.0f)

// ---------------- reductions ----------------
static __device__ __forceinline__ float wred_sum(float x){
#pragma unroll
  for (int o = 32; o; o >>= 1) x += __shfl_xor(x, o);
  return x;
}
static __device__ __forceinline__ int wred_sumi(int x){
#pragma unroll
  for (int o = 32; o; o >>= 1) x += __shfl_xor(x, o);
  return x;
}
static __device__ __forceinline__ float bred_sum(float x){
  __shared__ float r[4];
  x = wred_sum(x);
  if ((threadIdx.x & 63) == 0) r[threadIdx.x >> 6] = x;
  __syncthreads();
  float s = r[0] + r[1] + r[2] + r[3];
  __syncthreads();
  return s;
}

// ---------------- generic 128x128 f16 MFMA GEMM core ----------------
// global_load_lds width=16 staging with BOTH-SIDES XOR swizzle (rule #21):
// linear LDS dest; global SOURCE slot permuted (c&7)^((c>>3)&7); read applies
// the same XOR -> bank-conflict-free (verified: SQ_LDS_BANK_CONFLICT = 0).
template<class Epi>
static __device__ __forceinline__ void gemm_core(const f16* A, const f16* BT,
                                                 int m0, int K, int N, int n0, Epi epi)
{
  __shared__ __align__(16) f16 Al[BM][BKK];
  __shared__ __align__(16) f16 Bl[BN][BKK];
  const int t = threadIdx.x;
  const int lane = t & 63, wave = t >> 6;
  const int wr = wave >> 1, wc = wave & 1;

  // hoisted per-thread staging source pointers, slot XOR-swizzled by row&7
  const f16* gA[4];
  const f16* gB[4];
#pragma unroll
  for (int i = 0; i < 4; ++i) {
    int c = i * THREADS + t;
    int r = c >> 3;
    int kc = (((c & 7) ^ (r & 7)) << 3);
    gA[i] = A + (size_t)(m0 + r) * K + kc;
    gB[i] = BT + (size_t)(n0 + r) * K + kc;
  }

  f32x4 acc[4][4];
#pragma unroll
  for (int i = 0; i < 4; ++i)
#pragma unroll
    for (int j = 0; j < 4; ++j)
#pragma unroll
      for (int r = 0; r < 4; ++r) acc[i][j][r] = 0.0f;

  f16* Als = &Al[0][0];
  f16* Bls = &Bl[0][0];

  for (int k0 = 0; k0 < K; k0 += BKK) {
    __syncthreads();
#pragma unroll
    for (int i = 0; i < 4; ++i) {
      int c = i * THREADS + t;
      __builtin_amdgcn_global_load_lds(
          (const __attribute__((address_space(1))) void*)(gA[i] + k0),
          (__attribute__((address_space(3))) void*)(Als + (size_t)c * 8), 16, 0, 0);
      __builtin_amdgcn_global_load_lds(
          (const __attribute__((address_space(1))) void*)(gB[i] + k0),
          (__attribute__((address_space(3))) void*)(Bls + (size_t)c * 8), 16, 0, 0);
    }
    __syncthreads();
#pragma unroll
    for (int kk = 0; kk < BKK; kk += 32) {
      const int lrow = lane & 15, lk = (lane >> 4) * 8;
      const int sx = (lrow & 7) << 3;                 // read-side XOR (matches source)
      f16x8 af[4], bf[4];
#pragma unroll
      for (int mf = 0; mf < 4; ++mf)
        af[mf] = *(const f16x8*)&Als[(size_t)(wr * 64 + mf * 16 + lrow) * BKK + ((kk + lk) ^ sx)];
#pragma unroll
      for (int nf = 0; nf < 4; ++nf)
        bf[nf] = *(const f16x8*)&Bls[(size_t)(wc * 64 + nf * 16 + lrow) * BKK + ((kk + lk) ^ sx)];
#pragma unroll
      for (int mf = 0; mf < 4; ++mf)
#pragma unroll
        for (int nf = 0; nf < 4; ++nf)
          acc[mf][nf] = __builtin_amdgcn_mfma_f32_16x16x32_f16(af[mf], bf[nf], acc[mf][nf], 0, 0, 0);
    }
  }
  const int lr4 = (lane >> 4) * 4, lc = lane & 15;
#pragma unroll
  for (int mf = 0; mf < 4; ++mf)
#pragma unroll
    for (int nf = 0; nf < 4; ++nf)
#pragma unroll
      for (int r = 0; r < 4; ++r) {
        int row = wr * 64 + mf * 16 + lr4 + r;
        int col = n0 + wc * 64 + nf * 16 + lc;
        epi(row, col, acc[mf][nf][r]);
      }
}

// ---------------- kernels ----------------
__global__ __launch_bounds__(256) void k_cvt(const float* x, f16* o){
  size_t i = (size_t)blockIdx.x * 256 + threadIdx.x;
  float4 v = ((const float4*)x)[i];
  f16x4v h;
  h[0] = (f16)v.x; h[1] = (f16)v.y; h[2] = (f16)v.z; h[3] = (f16)v.w;
  *(f16x4v*)(o + i * 4) = h;
}

// 64x64-tile transpose, vectorized: in fp32 [Kd][Nd] -> out f16 [Nd][Kd] * WSCALE.
// float4 loads (256B/16 lanes), f16x4 stores (128B/16 lanes); LDS [64][65]
// column reads land 2-way (free).
__global__ __launch_bounds__(256) void k_transpose(const float* in, f16* out, int Kd, int Nd){
  __shared__ float tl[64][65];
  const float* ip = in + (size_t)blockIdx.z * Kd * Nd;
  f16* op = out + (size_t)blockIdx.z * Kd * Nd;
  int n0 = blockIdx.x * 64, k0 = blockIdx.y * 64;
  int tx = threadIdx.x & 15, ty = threadIdx.x >> 4;   // tx: n-quad, ty: row
#pragma unroll
  for (int j = 0; j < 64; j += 16) {
    float4 v = *(const float4*)(ip + (size_t)(k0 + ty + j) * Nd + n0 + tx * 4);
    tl[ty + j][tx * 4 + 0] = v.x;
    tl[ty + j][tx * 4 + 1] = v.y;
    tl[ty + j][tx * 4 + 2] = v.z;
    tl[ty + j][tx * 4 + 3] = v.w;
  }
  __syncthreads();
#pragma unroll
  for (int j = 0; j < 64; j += 16) {
    f16x4v h;
    h[0] = (f16)(tl[tx * 4 + 0][ty + j] * WSCALE);
    h[1] = (f16)(tl[tx * 4 + 1][ty + j] * WSCALE);
    h[2] = (f16)(tl[tx * 4 + 2][ty + j] * WSCALE);
    h[3] = (f16)(tl[tx * 4 + 3][ty + j] * WSCALE);
    *(f16x4v*)(op + (size_t)(n0 + ty + j) * Kd + k0 + tx * 4) = h;
  }
}

__global__ __launch_bounds__(256) void k_gemm_qkv(const f16* xb,
    const f16* wqT, const f16* wkT, const f16* wvT,
    const float* bq, const float* bk, const float* bv,
    f16* Q, f16* Ko, f16* V)
{
  int m0 = blockIdx.x * 128, n0 = blockIdx.y * 128, z = blockIdx.z;
  const f16* BT = (z == 0) ? wqT : ((z == 1) ? wkT : wvT);
  const float* bias = (z == 0) ? bq : ((z == 1) ? bk : bv);
  auto epi = [&](int row, int col, float vv) {
    int grow = m0 + row;
    int b = grow >> 11, s = grow & 2047;
    int h = col >> 6, dh = col & 63;
    float val = vv * WDESCALE + bias[col];
    if (z == 2) V[(((size_t)b * 12 + h) * 64 + dh) * 2048 + s] = (f16)val;
    else ((z == 0) ? Q : Ko)[(((size_t)b * 12 + h) * 2048 + s) * 64 + dh] = (f16)val;
  };
  gemm_core(xb, BT, m0, 768, 768, n0, epi);
}

// ---------------- fused flash attention (v3: split-KV, additive combine) ----
__global__ __launch_bounds__(256, 4) void k_fattn(const f16* Qf, const f16* Kf,
                                                  const f16* Vf, float* Opart, float* lpart)
{
  __shared__ __align__(16) f16 Kl[64][72];
  __shared__ __align__(16) f16 Vl[64][72];
  __shared__ __align__(16) f16 Pl[64][72];
  const int t = threadIdx.x, lane = t & 63, wid = t >> 6;
  const int lc = lane & 15, g = lane >> 4;
  const int q0 = blockIdx.x * 64, bh = blockIdx.y, sp = blockIdx.z;
  const f16* Qh = Qf + (size_t)bh * 2048 * 64;
  const f16* Kh = Kf + ((size_t)bh * 2048 + sp * 1024) * 64;
  const f16* Vh = Vf + (size_t)bh * 64 * 2048 + sp * 1024;

  const float C1 = 0.125f * 1.44269504f;
  const float C2 = 9.0f - 2.0f * 1.44269504f;

  f16x8 aq[2];
#pragma unroll
  for (int kk = 0; kk < 2; ++kk)
    aq[kk] = *(const f16x8*)(Qh + (size_t)(q0 + wid * 16 + lc) * 64 + kk * 32 + g * 8);

  f32x4 acco[4];
  float l_[4];
#pragma unroll
  for (int nf = 0; nf < 4; ++nf)
#pragma unroll
    for (int r = 0; r < 4; ++r) acco[nf][r] = 0.f;
#pragma unroll
  for (int r = 0; r < 4; ++r) l_[r] = 0.f;

  f16x8 sk[2], sv[2];
#pragma unroll
  for (int i = 0; i < 2; ++i) {
    int c = i * 256 + t;
    sk[i] = *(const f16x8*)(Kh + (size_t)(c >> 3) * 64 + (c & 7) * 8);
    sv[i] = *(const f16x8*)(Vh + (size_t)(c >> 3) * 2048 + (c & 7) * 8);
  }

  for (int j = 0; j < 16; ++j) {
    __syncthreads();
#pragma unroll
    for (int i = 0; i < 2; ++i) {
      int c = i * 256 + t;
      *(f16x8*)&Kl[c >> 3][(c & 7) * 8] = sk[i];
      *(f16x8*)&Vl[c >> 3][(c & 7) * 8] = sv[i];
    }
    __syncthreads();

    if (j < 15) {
      const int kv1 = (j + 1) * 64;
#pragma unroll
      for (int i = 0; i < 2; ++i) {
        int c = i * 256 + t;
        sk[i] = *(const f16x8*)(Kh + (size_t)(kv1 + (c >> 3)) * 64 + (c & 7) * 8);
        sv[i] = *(const f16x8*)(Vh + (size_t)(c >> 3) * 2048 + kv1 + (c & 7) * 8);
      }
    }

    f32x4 acc[4];
#pragma unroll
    for (int nf = 0; nf < 4; ++nf)
#pragma unroll
      for (int r = 0; r < 4; ++r) acc[nf][r] = 0.f;
#pragma unroll
    for (int kk = 0; kk < 2; ++kk) {
      f16x8 bk[4];
#pragma unroll
      for (int nf = 0; nf < 4; ++nf) bk[nf] = *(const f16x8*)&Kl[nf * 16 + lc][kk * 32 + g * 8];
#pragma unroll
      for (int nf = 0; nf < 4; ++nf)
        acc[nf] = __builtin_amdgcn_mfma_f32_16x16x32_f16(aq[kk], bk[nf], acc[nf], 0, 0, 0);
    }

    {
      const int prow = wid * 16 + g * 4;
#pragma unroll
      for (int r = 0; r < 4; ++r) {
        float ls = 0.f;
#pragma unroll
        for (int nf = 0; nf < 4; ++nf) {
          float p = exp2f(fmaf(acc[nf][r], C1, C2));   // = 512*exp(score-2)
          Pl[prow + r][nf * 16 + lc] = (f16)p;
          ls += p;
        }
        l_[r] += ls;
      }
    }

#pragma unroll
    for (int kk = 0; kk < 2; ++kk) {
      f16x8 ap, bv[4];
      ap = *(const f16x8*)&Pl[wid * 16 + lc][kk * 32 + g * 8];
#pragma unroll
      for (int nf = 0; nf < 4; ++nf) bv[nf] = *(const f16x8*)&Vl[nf * 16 + lc][kk * 32 + g * 8];
#pragma unroll
      for (int nf = 0; nf < 4; ++nf)
        acco[nf] = __builtin_amdgcn_mfma_f32_16x16x32_f16(ap, bv[nf], acco[nf], 0, 0, 0);
    }
  }

  float* Op = Opart + ((size_t)(sp * 24 + bh) * 2048 + q0) * 64;
  float* lp = lpart + (size_t)(sp * 24 + bh) * 2048 + q0;
#pragma unroll
  for (int r = 0; r < 4; ++r) {
    float lr = l_[r];
#pragma unroll
    for (int o = 1; o < 16; o <<= 1) lr += __shfl_xor(lr, o);
    if (lc == 0) lp[wid * 16 + g * 4 + r] = lr;
#pragma unroll
    for (int nf = 0; nf < 4; ++nf)
      Op[(size_t)(wid * 16 + g * 4 + r) * 64 + nf * 16 + lc] = acco[nf][r];
  }
}

// combine: ctx = (O0+O1)/(l0+l1); 4 elems/thread
__global__ __launch_bounds__(256) void k_attcomb(const float* Opart, const float* lpart, f16* ctx){
  size_t base = ((size_t)blockIdx.x * 256 + threadIdx.x) * 4;   // over 24*2048*64
  size_t row = base >> 6; int dh = base & 63;
  int bh = (int)(row >> 11), qr = (int)(row & 2047);
  int b = bh / 12, h = bh - b * 12;
  const float4 o0 = *(const float4*)(Opart + base);
  const float4 o1 = *(const float4*)(Opart + base + (size_t)24 * 2048 * 64);
  float inv = 1.f / (lpart[row] + lpart[row + 24 * 2048]);
  f16x4v hv;
  hv[0] = (f16)((o0.x + o1.x) * inv);
  hv[1] = (f16)((o0.y + o1.y) * inv);
  hv[2] = (f16)((o0.z + o1.z) * inv);
  hv[3] = (f16)((o0.w + o1.w) * inv);
  *(f16x4v*)(ctx + ((size_t)b * 2048 + qr) * 768 + h * 64 + dh) = hv;
}

__global__ __launch_bounds__(256) void k_gemm_oproj(const f16* ctx, const f16* woT,
    const float* bo, const float* x, float* x1pre)
{
  int m0 = blockIdx.x * 128, n0 = blockIdx.y * 128;
  auto epi = [&](int row, int col, float vv) {
    size_t i = (size_t)(m0 + row) * 768 + col;
    x1pre[i] = x[i] + vv * WDESCALE + bo[col];
  };
  gemm_core(ctx, woT, m0, 768, 768, n0, epi);
}

__global__ __launch_bounds__(256) void k_ln(const float* in, const float* add,
    const float* g, const float* b, float* outf, f16* outh)
{
  size_t row = blockIdx.x;
  int t = threadIdx.x;
  const float* p = in + row * 768;
  float v[3];
  float s = 0.f;
#pragma unroll
  for (int i = 0; i < 3; ++i) {
    float xv = p[t + i * 256];
    if (add) xv += add[row * 768 + t + i * 256];
    v[i] = xv; s += xv;
  }
  float mu = bred_sum(s) * (1.f / 768.f);
  float q = 0.f;
#pragma unroll
  for (int i = 0; i < 3; ++i) { float d = v[i] - mu; q += d * d; }
  float var = bred_sum(q) * (1.f / 768.f);
  float inv = rsqrtf(var + 1e-5f);
#pragma unroll
  for (int i = 0; i < 3; ++i) {
    int c = t + i * 256;
    float y = (v[i] - mu) * inv * g[c] + b[c];
    outf[row * 768 + c] = y;
    if (outh) outh[row * 768 + c] = (f16)y;
  }
}

// fused MoE-combine + LayerNorm: val = x1 + g0*y[slot0] + g1*y[slot1], then LN
__global__ __launch_bounds__(256) void k_ln_moe(const float* x1, const f16* ys,
    const int* inv_map, const float* gates, const float* g, const float* b, float* outf)
{
  size_t row = blockIdx.x;
  int t = threadIdx.x;
  int sl0 = inv_map[row * 2], sl1 = inv_map[row * 2 + 1];
  float g0 = gates[row * 2], g1 = gates[row * 2 + 1];
  const float* p = x1 + row * 768;
  const f16* y0 = ys + (size_t)sl0 * 768;
  const f16* y1 = ys + (size_t)sl1 * 768;
  float v[3];
  float s = 0.f;
#pragma unroll
  for (int i = 0; i < 3; ++i) {
    int c = t + i * 256;
    float xv = p[c] + g0 * (float)y0[c] + g1 * (float)y1[c];
    v[i] = xv; s += xv;
  }
  float mu = bred_sum(s) * (1.f / 768.f);
  float q = 0.f;
#pragma unroll
  for (int i = 0; i < 3; ++i) { float d = v[i] - mu; q += d * d; }
  float var = bred_sum(q) * (1.f / 768.f);
  float inv = rsqrtf(var + 1e-5f);
#pragma unroll
  for (int i = 0; i < 3; ++i) {
    int c = t + i * 256;
    outf[row * 768 + c] = (v[i] - mu) * inv * g[c] + b[c];
  }
}

// one wave per token. mode 1: write topi+gates (NO atomics).
// mode 2: per-block partial probsum/top2-count -> pprob_part/pcnt_part [block][8].
__global__ __launch_bounds__(256) void k_router(const float* X, const float* rw, const float* rb,
    int* topi, float* gates, float* pprob_part, int* pcnt_part, int mode)
{
  __shared__ float sp[4][8];
  __shared__ int   si[4][2];
  int wave = threadIdx.x >> 6;
  int tok = blockIdx.x * 4 + wave;
  int lane = threadIdx.x & 63;
  const float* xr = X + (size_t)tok * 768;
  float a0=0,a1=0,a2=0,a3=0,a4=0,a5=0,a6=0,a7=0;
#pragma unroll
  for (int i = 0; i < 12; ++i) {
    int d = lane + i * 64;
    float xv = xr[d];
    float4 w0 = *(const float4*)(rw + d * 8);
    float4 w1 = *(const float4*)(rw + d * 8 + 4);
    a0 += xv*w0.x; a1 += xv*w0.y; a2 += xv*w0.z; a3 += xv*w0.w;
    a4 += xv*w1.x; a5 += xv*w1.y; a6 += xv*w1.z; a7 += xv*w1.w;
  }
  a0=wred_sum(a0); a1=wred_sum(a1); a2=wred_sum(a2); a3=wred_sum(a3);
  a4=wred_sum(a4); a5=wred_sum(a5); a6=wred_sum(a6); a7=wred_sum(a7);
  if (lane == 0) {
    float lg[8] = {a0+rb[0],a1+rb[1],a2+rb[2],a3+rb[3],a4+rb[4],a5+rb[5],a6+rb[6],a7+rb[7]};
    float mx = lg[0];
    for (int e = 1; e < 8; ++e) mx = fmaxf(mx, lg[e]);
    float pp[8], ssum = 0.f;
    for (int e = 0; e < 8; ++e) { pp[e] = expf(lg[e] - mx); ssum += pp[e]; }
    float invs = 1.f / ssum;
    for (int e = 0; e < 8; ++e) pp[e] *= invs;
    int i1 = 0; float p1 = pp[0];
    for (int e = 1; e < 8; ++e) if (pp[e] > p1) { p1 = pp[e]; i1 = e; }
    int i2 = -1; float p2 = -1.f;
    for (int e = 0; e < 8; ++e) if (e != i1 && pp[e] > p2) { p2 = pp[e]; i2 = e; }
    if (mode == 1) {
      float gs = 1.f / (p1 + p2);
      topi[tok*2] = i1; topi[tok*2+1] = i2;
      gates[tok*2] = p1*gs; gates[tok*2+1] = p2*gs;
    } else {
      for (int e = 0; e < 8; ++e) sp[wave][e] = pp[e];
      si[wave][0] = i1; si[wave][1] = i2;
    }
  }
  if (mode == 2) {
    __syncthreads();
    int t = threadIdx.x;
    if (t < 8) {
      float s = sp[0][t] + sp[1][t] + sp[2][t] + sp[3][t];
      int c = 0;
#pragma unroll
      for (int w = 0; w < 4; ++w) c += (si[w][0] == t) + (si[w][1] == t);
      pprob_part[blockIdx.x * 8 + t] = s;
      pcnt_part[blockIdx.x * 8 + t] = c;
    }
  }
}

// single block: histogram of topi, then serial tile plans.
// Experts padded to 256 rows. tile_e/tile_r0: 256-row tiles (moe1, cap 40);
// tile_e2/tile_r02: 128-row tiles over the same ranges (moe2, cap 80).
__global__ __launch_bounds__(256) void k_plan(const int* topi, int* offal,
    int* tile_e, int* tile_r0, int* tile_e2, int* tile_r02)
{
  __shared__ int hist[8];
  int t = threadIdx.x, lane = t & 63;
  if (t < 8) hist[t] = 0;
  __syncthreads();
  int loc[8] = {0,0,0,0,0,0,0,0};
  for (int i = t; i < 8192; i += 256) ++loc[topi[i]];
#pragma unroll
  for (int e = 0; e < 8; ++e) {
    int s = wred_sumi(loc[e]);
    if (lane == 0) atomicAdd(&hist[e], s);
  }
  __syncthreads();
  if (t == 0) {
    int off = 0, t1 = 0, t2 = 0;
    for (int e = 0; e < 8; ++e) {
      offal[e] = off;
      int nt = (hist[e] + 255) >> 8;
      for (int i = 0; i < nt; ++i) {
        tile_e[t1] = e; tile_r0[t1] = off + i * 256; ++t1;
        tile_e2[t2] = e; tile_r02[t2] = off + i * 256; ++t2;
        tile_e2[t2] = e; tile_r02[t2] = off + i * 256 + 128; ++t2;
      }
      off += nt << 8;
    }
    for (; t1 < 40; ++t1) { tile_e[t1] = -1; tile_r0[t1] = 0; }
    for (; t2 < 80; ++t2) { tile_e2[t2] = -1; tile_r02[t2] = 0; }
  }
}

// one block, 8 waves; wave w compacts expert w's slots via ballot prefix (no atomics)
// also records inverse map: inv[tok*2+k] = slot
__global__ __launch_bounds__(512) void k_scatter(const int* topi, const float* gates,
    const int* offal, int* perm, float* gate_s, int* inv_map)
{
  int w = threadIdx.x >> 6, lane = threadIdx.x & 63;
  int base = offal[w];
  for (int it = 0; it < 128; ++it) {
    int i = it * 64 + lane;
    int e = topi[i];
    bool act = (e == w);
    unsigned long long mask = __ballot(act);
    if (act) {
      int pos = base + __popcll(mask & ((1ull << lane) - 1ull));
      perm[pos] = i >> 1;
      gate_s[pos] = gates[i];
      inv_map[i] = pos;
    }
    base += __popcll(mask);
  }
}

// ---------------- moe1: 256x256 tile, 512 thr, dbuf, COUNTED-vmcnt pipeline --
__global__ __launch_bounds__(512, 1) void k_gemm_moe1(const f16* x1b, const f16* ew1T,
    const float* eb1, const int* tile_e, const int* tile_r0, const int* perm, f16* hbuf)
{
  __shared__ __align__(16) f16 Al[2][256][64];
  __shared__ __align__(16) f16 Bl[2][256][64];
  int e = tile_e[blockIdx.x];
  if (e < 0) return;
  int s0 = tile_r0[blockIdx.x];
  int n0 = blockIdx.y * 256;
  const f16* BT = ew1T + (size_t)e * 3072 * 768 + (size_t)n0 * 768;
  const float* be = eb1 + e * 3072;

  const int t = threadIdx.x;               // 0..511
  const int lane = t & 63, wave = t >> 6;  // 8 waves
  const int wr = wave >> 2, wc = wave & 3; // 2 x 4

  const f16* gA[4];
  const f16* gB[4];
#pragma unroll
  for (int i = 0; i < 4; ++i) {
    int c = i * 512 + t;                   // 0..2047
    int r = c >> 3;                        // 0..255
    int kc = (((c & 7) ^ (r & 7)) << 3);
    gA[i] = x1b + (size_t)perm[s0 + r] * 768 + kc;
    gB[i] = BT + (size_t)r * 768 + kc;
  }

  f32x4 acc[8][4];
#pragma unroll
  for (int i = 0; i < 8; ++i)
#pragma unroll
    for (int j = 0; j < 4; ++j)
#pragma unroll
      for (int r = 0; r < 4; ++r) acc[i][j][r] = 0.0f;

  auto stage = [&](int buf, int k0) {
    f16* Ad = &Al[buf][0][0];
    f16* Bd = &Bl[buf][0][0];
#pragma unroll
    for (int i = 0; i < 4; ++i) {
      int c = i * 512 + t;
      __builtin_amdgcn_global_load_lds(
          (const __attribute__((address_space(1))) void*)(gA[i] + k0),
          (__attribute__((address_space(3))) void*)(Ad + (size_t)c * 8), 16, 0, 0);
      __builtin_amdgcn_global_load_lds(
          (const __attribute__((address_space(1))) void*)(gB[i] + k0),
          (__attribute__((address_space(3))) void*)(Bd + (size_t)c * 8), 16, 0, 0);
    }
  };

  // prologue: two K-tiles in flight
  stage(0, 0);
  stage(1, 64);

  for (int ks = 0; ks < 12; ++ks) {
    const int cur = ks & 1;
    if (ks < 11) asm volatile("s_waitcnt vmcnt(8)" ::: "memory");
    else         asm volatile("s_waitcnt vmcnt(0)" ::: "memory");
    __builtin_amdgcn_s_barrier();
    asm volatile("" ::: "memory");

    const f16* Ab = &Al[cur][0][0];
    const f16* Bb = &Bl[cur][0][0];
#pragma unroll
    for (int kk = 0; kk < 64; kk += 32) {
      const int lrow = lane & 15, lk = (lane >> 4) * 8;
      const int sx = (lrow & 7) << 3;
      f16x8 af[8], bf[4];
#pragma unroll
      for (int mf = 0; mf < 8; ++mf)
        af[mf] = *(const f16x8*)&Ab[(size_t)(wr * 128 + mf * 16 + lrow) * 64 + ((kk + lk) ^ sx)];
#pragma unroll
      for (int nf = 0; nf < 4; ++nf)
        bf[nf] = *(const f16x8*)&Bb[(size_t)(wc * 64 + nf * 16 + lrow) * 64 + ((kk + lk) ^ sx)];
#pragma unroll
      for (int mf = 0; mf < 8; ++mf)
#pragma unroll
        for (int nf = 0; nf < 4; ++nf)
          acc[mf][nf] = __builtin_amdgcn_mfma_f32_16x16x32_f16(af[mf], bf[nf], acc[mf][nf], 0, 0, 0);
    }

    asm volatile("" ::: "memory");
    __builtin_amdgcn_s_barrier();
    asm volatile("" ::: "memory");
    if (ks < 10) stage(cur, (ks + 2) * 64);
  }

  const int lr4 = (lane >> 4) * 4, lc = lane & 15;
#pragma unroll
  for (int mf = 0; mf < 8; ++mf)
#pragma unroll
    for (int nf = 0; nf < 4; ++nf)
#pragma unroll
      for (int r = 0; r < 4; ++r) {
        int row = wr * 128 + mf * 16 + lr4 + r;
        int col = n0 + wc * 64 + nf * 16 + lc;
        hbuf[(size_t)(s0 + row) * 3072 + col] = (f16)fmaxf(acc[mf][nf][r] * WDESCALE + be[col], 0.f);
      }
}

// moe2: 128x128 2-phase core, grid (80,6) tile-fastest (B-panel reuse; R12-best)
__global__ __launch_bounds__(256) void k_gemm_moe2(const f16* hbuf, const f16* ew2T,
    const float* eb2, const int* tile_e2, const int* tile_r02, f16* yslots)
{
  int e = tile_e2[blockIdx.x];
  if (e < 0) return;
  int s0 = tile_r02[blockIdx.x];
  int n0 = blockIdx.y * 128;
  const f16* A = hbuf + (size_t)s0 * 3072;
  const f16* BT = ew2T + (size_t)e * 768 * 3072;
  const float* be = eb2 + e * 768;
  auto epi = [&](int row, int col, float vv) {
    yslots[(size_t)(s0 + row) * 768 + col] = (f16)(vv * WDESCALE + be[col]);
  };
  gemm_core(A, BT, 0, 3072, 768, n0, epi);
}

// reduce [1024][8] partials -> aux loss (MUST be launched with 256 threads)
__global__ __launch_bounds__(256) void k_final(const float* pprob, const int* pcnt, float* out){
  __shared__ float sp[256];
  __shared__ int sc[256];
  int t = threadIdx.x, e = t & 7, g = t >> 3;
  float s = 0.f; int c = 0;
  for (int b = g; b < 1024; b += 32) { s += pprob[b * 8 + e]; c += pcnt[b * 8 + e]; }
  sp[t] = s; sc[t] = c;
  __syncthreads();
  if (t < 8) {
    float ss = 0.f; int cc = 0;
    for (int g2 = 0; g2 < 32; ++g2) { ss += sp[t + g2 * 8]; cc += sc[t + g2 * 8]; }
    sp[t] = ss; sc[t] = cc;
  }
  __syncthreads();
  if (t == 0) {
    float a = 0.f;
    for (int e2 = 0; e2 < 8; ++e2)
      a += ((float)sc[e2] * (1.f / 8192.f)) * (sp[e2] * (1.f / 4096.f));
    out[(size_t)4096 * 768] = 8.f * a;
  }
}

// ---------------- host ----------------
extern "C" void kernel_launch(void* const* d_in, const int* in_sizes, int n_in,
                              void* d_out, int out_size, void* d_ws, size_t ws_size,
                              hipStream_t stream)
{
  const float* x   = (const float*)d_in[0];
  const float* wq  = (const float*)d_in[1];
  const float* bq  = (const float*)d_in[2];
  const float* wk  = (const float*)d_in[3];
  const float* bk  = (const float*)d_in[4];
  const float* wv  = (const float*)d_in[5];
  const float* bv  = (const float*)d_in[6];
  const float* wo  = (const float*)d_in[7];
  const float* bo  = (const float*)d_in[8];
  const float* n1g = (const float*)d_in[9];
  const float* n1b = (const float*)d_in[10];
  const float* rw  = (const float*)d_in[11];
  const float* rb  = (const float*)d_in[12];
  const float* ew1 = (const float*)d_in[13];
  const float* eb1 = (const float*)d_in[14];
  const float* ew2 = (const float*)d_in[15];
  const float* eb2 = (const float*)d_in[16];
  const float* n2g = (const float*)d_in[17];
  const float* n2b = (const float*)d_in[18];
  float* out = (float*)d_out;
  char* ws = (char*)d_ws;

  size_t oWQT,oWKT,oWVT,oWOT,oEW1T,oEW2T,oXB,oQ,oK,oV,oCTX,oX1,oX1B,oYS;
  size_t oTOPI,oGATES,oOFF,oTE,oTR,oTE2,oTR2,oPERM,oGS,oINV,oH,oPP,oPC,oOP,oLP;

  {
    size_t off = 0;
    auto al = [&](size_t bytes) { size_t o = off; off += (bytes + 255) & ~(size_t)255; return o; };
    oWQT = al((size_t)768*768*2); oWKT = al((size_t)768*768*2);
    oWVT = al((size_t)768*768*2); oWOT = al((size_t)768*768*2);
    oEW1T = al((size_t)8*768*3072*2); oEW2T = al((size_t)8*768*3072*2);
    oXB  = al((size_t)4096*768*2);
    oQ   = al((size_t)24*2048*64*2); oK = al((size_t)24*2048*64*2); oV = al((size_t)24*2048*64*2);
    oCTX = al((size_t)4096*768*2);
    oX1  = al((size_t)4096*768*4);
    oX1B = al((size_t)4096*768*2);
    oYS  = al((size_t)10240*768*2);
    oTOPI = al(4096*2*4); oGATES = al(4096*2*4);
    oOFF = al(256);
    oTE = al(256); oTR = al(256); oTE2 = al(512); oTR2 = al(512);
    oPERM = al(10240*4); oGS = al(10240*4); oINV = al(8192*4);
    oH = al((size_t)10240*3072*2);
    oPP = al(1024*8*4); oPC = al(1024*8*4);
    oOP = al((size_t)2*24*2048*64*4);
    oLP = al((size_t)2*24*2048*4);
    (void)ws_size;
  }

  f16* wqT  = (f16*)(ws + oWQT);
  f16* wkT  = (f16*)(ws + oWKT);
  f16* wvT  = (f16*)(ws + oWVT);
  f16* woT  = (f16*)(ws + oWOT);
  f16* ew1T = (f16*)(ws + oEW1T);
  f16* ew2T = (f16*)(ws + oEW2T);
  f16* xb   = (f16*)(ws + oXB);
  f16* Qf   = (f16*)(ws + oQ);
  f16* Kf   = (f16*)(ws + oK);
  f16* Vf   = (f16*)(ws + oV);
  f16* ctxb = (f16*)(ws + oCTX);
  float* x1 = (float*)(ws + oX1);
  f16* x1bb = (f16*)(ws + oX1B);
  f16* yslots = (f16*)(ws + oYS);
  int* topi = (int*)(ws + oTOPI);
  float* gates = (float*)(ws + oGATES);
  int* offal  = (int*)(ws + oOFF);
  int* tile_e = (int*)(ws + oTE);
  int* tile_r0= (int*)(ws + oTR);
  int* tile_e2 = (int*)(ws + oTE2);
  int* tile_r02= (int*)(ws + oTR2);
  int* perm   = (int*)(ws + oPERM);
  float* gate_s = (float*)(ws + oGS);
  int* inv_map = (int*)(ws + oINV);
  f16* hbuf   = (f16*)(ws + oH);
  float* pprob = (float*)(ws + oPP);
  int* pcnt   = (int*)(ws + oPC);
  float* Opart = (float*)(ws + oOP);
  float* lpart = (float*)(ws + oLP);

  (void)in_sizes; (void)n_in; (void)out_size;

  // zero: perm/gate_s padding (contiguous, 10240 each)
  hipMemsetAsync(ws + oPERM, 0, 2 * 10240 * 4, stream);

  // convert inputs (vectorized 64x64 transposes)
  k_cvt<<<3072, 256, 0, stream>>>(x, xb);
  k_transpose<<<dim3(12,12,1), 256, 0, stream>>>(wq, wqT, 768, 768);
  k_transpose<<<dim3(12,12,1), 256, 0, stream>>>(wk, wkT, 768, 768);
  k_transpose<<<dim3(12,12,1), 256, 0, stream>>>(wv, wvT, 768, 768);
  k_transpose<<<dim3(12,12,1), 256, 0, stream>>>(wo, woT, 768, 768);
  k_transpose<<<dim3(48,12,8), 256, 0, stream>>>(ew1, ew1T, 768, 3072);
  k_transpose<<<dim3(12,48,8), 256, 0, stream>>>(ew2, ew2T, 3072, 768);

  // attention: QKV projection + fused flash attention (split-KV) + combine
  k_gemm_qkv<<<dim3(32,6,3), 256, 0, stream>>>(xb, wqT, wkT, wvT, bq, bk, bv, Qf, Kf, Vf);
  k_fattn<<<dim3(32,24,2), 256, 0, stream>>>(Qf, Kf, Vf, Opart, lpart);
  k_attcomb<<<3072, 256, 0, stream>>>(Opart, lpart, ctxb);
  k_gemm_oproj<<<dim3(32,6), 256, 0, stream>>>(ctxb, woT, bo, x, x1);
  k_ln<<<4096, 256, 0, stream>>>(x1, nullptr, n1g, n1b, x1, x1bb);

  // MoE routing + grouped experts (atomic-free end to end)
  k_router<<<1024, 256, 0, stream>>>(x1, rw, rb, topi, gates, pprob, pcnt, 1);
  k_plan<<<1, 256, 0, stream>>>(topi, offal, tile_e, tile_r0, tile_e2, tile_r02);
  k_scatter<<<1, 512, 0, stream>>>(topi, gates, offal, perm, gate_s, inv_map);
  k_gemm_moe1<<<dim3(40,12), 512, 0, stream>>>(x1bb, ew1T, eb1, tile_e, tile_r0, perm, hbuf);
  k_gemm_moe2<<<dim3(80,6), 256, 0, stream>>>(hbuf, ew2T, eb2, tile_e2, tile_r02, yslots);

  // fused combine + final LN -> output, then aux loss
  k_ln_moe<<<4096, 256, 0, stream>>>(x1, yslots, inv_map, gates, n2g, n2b, out);
  k_router<<<1024, 256, 0, stream>>>(out, rw, rb, topi, gates, pprob, pcnt, 2);
  k_final<<<1, 256, 0, stream>>>(pprob, pcnt, out);
}